// Round 19
// baseline (228.328 us; speedup 1.0000x reference)
//
#include <hip/hip_runtime.h>

typedef unsigned short u16;
typedef unsigned int u32;
typedef unsigned long long u64;
typedef __attribute__((ext_vector_type(8))) short bf16x8;
typedef __attribute__((ext_vector_type(4))) float f32x4;

#define BATCH 4
#define SEQ 2048
#define HID 1024
#define NHEAD 16
#define HDIM 64
// att_scale * log2(e): p = exp2(raw_score * C1); folded into Q at proj epilogue
#define C1 0.18033688011112042f

#if __has_builtin(__builtin_amdgcn_exp2f)
#define EXP2(x) __builtin_amdgcn_exp2f(x)
#else
#define EXP2(x) exp2f(x)
#endif

__device__ __forceinline__ u16 f2bf(float f) {
    u32 u = __builtin_bit_cast(u32, f);
    u += 0x7fffu + ((u >> 16) & 1u);
    return (u16)(u >> 16);
}

__device__ __forceinline__ void gl_lds16(const void* g, void* l) {
    __builtin_amdgcn_global_load_lds((const __attribute__((address_space(1))) u32*)g,
                                     (__attribute__((address_space(3))) u32*)l, 16, 0, 0);
}

// ---------------- front: convxv (0-511) | transw (512-2559) | flagk (2560) --
// convxv: x fp32 -> bf16 AND value = x @ W_v (one x read serves both).
//   NOTE: h4 iterated in uniform order across threads -> Wv operands are
//   wave-uniform per step (compiler hoists to scalar/broadcast loads).
//   Do NOT rotate per-lane (R15 regression: broke the broadcast, +9 us).
// transw: W_qk (1024x2048) -> wT bf16 (2048x1024).
// flagk: mask dtype probe -> flag=1 int32 mask, 0 byte mask.
__global__ __launch_bounds__(256) void front(const float* __restrict__ x,
                                             const float* __restrict__ Wv,
                                             const float* __restrict__ W,
                                             const unsigned char* __restrict__ mask,
                                             u16* __restrict__ xb,
                                             float* __restrict__ vT,
                                             u16* __restrict__ wT,
                                             int* __restrict__ flag) {
    __shared__ __align__(16) float smem[16 * 1024];  // 64 KB, role-cast below
    int bid = blockIdx.x;
    if (bid < 512) {
        // ---- convxv ----
        float* xs = smem;
        int s0 = bid * 16;
        const float4* xg = (const float4*)(x + (size_t)s0 * HID);
        float4* xd = (float4*)xs;
        ushort4* xo = (ushort4*)(xb + (size_t)s0 * HID);
#pragma unroll
        for (int j = 0; j < 16; ++j) {
            int i = j * 256 + threadIdx.x;
            float4 v = xg[i];
            xd[i] = v;
            ushort4 o;
            o.x = f2bf(v.x); o.y = f2bf(v.y); o.z = f2bf(v.z); o.w = f2bf(v.w);
            xo[i] = o;
        }
        __syncthreads();
        int sl = threadIdx.x >> 4, n = threadIdx.x & 15;
        const float4* xrow = (const float4*)&xs[sl * HID];
        float acc = 0.f;
        for (int h4 = 0; h4 < 256; ++h4) {
            float4 xv = xrow[h4];
            acc += xv.x * Wv[(h4 * 4 + 0) * 16 + n] + xv.y * Wv[(h4 * 4 + 1) * 16 + n]
                 + xv.z * Wv[(h4 * 4 + 2) * 16 + n] + xv.w * Wv[(h4 * 4 + 3) * 16 + n];
        }
        int s = s0 + sl;
        int b = s >> 11, q = s & 2047;
        vT[((size_t)b * 16 + n) * SEQ + q] = acc;
    } else if (bid < 2560) {
        // ---- transw ----
        float (*t)[33] = (float (*)[33])smem;
        int tb = bid - 512;
        int nb = tb & 63, hb = tb >> 6;
        int tx = threadIdx.x & 31, ty = threadIdx.x >> 5;
#pragma unroll
        for (int i = 0; i < 4; ++i)
            t[ty + i * 8][tx] = W[(size_t)(hb * 32 + ty + i * 8) * 2048 + nb * 32 + tx];
        __syncthreads();
#pragma unroll
        for (int i = 0; i < 4; ++i)
            wT[(size_t)(nb * 32 + ty + i * 8) * 1024 + hb * 32 + tx] = f2bf(t[tx][ty + i * 8]);
    } else {
        // ---- flagk: probe first 64 KB of mask ----
        int* any = (int*)smem;
        if (threadIdx.x == 0) *any = 0;
        __syncthreads();
        const uint4* m4 = (const uint4*)mask;
        u32 acc = 0;
#pragma unroll
        for (int j = 0; j < 16; ++j) {
            uint4 v = m4[threadIdx.x + j * 256];
            acc |= (v.x | v.y | v.z | v.w) & 0xFFFFFF00u;
        }
        if (acc) atomicOr(any, 1);
        __syncthreads();
        if (threadIdx.x == 0) *flag = (*any == 0) ? 1 : 0;
    }
}

// ---------------- bitpack mask: KEEP-bits (1 = unmasked) via ballot ---------
__global__ void bitpack(const void* __restrict__ mask, const int* __restrict__ flag,
                        u64* __restrict__ bm) {
    int base = blockIdx.x * 2048 + threadIdx.x;  // grid 8192, covers 16777216
    int fl = *flag;
#pragma unroll
    for (int k = 0; k < 8; ++k) {
        int i = base + k * 256;
        int v;
        if (fl) v = ((const int*)mask)[i];
        else    v = ((const unsigned char*)mask)[i];
        u64 bits = __ballot(v == 0);  // keep-bit; lanes cover consecutive i
        if ((threadIdx.x & 63) == 0) bm[i >> 6] = bits;
    }
}

// ---------------- proj GEMM: qkb(8192x2048) = xb(8192x1024) @ wT^T ----------
// 128x128 tile, BK=64, double-buffered LDS (64 KB), counted pipeline.
__global__ __launch_bounds__(256) void proj_gemm(const u16* __restrict__ xb,
                                                 const u16* __restrict__ wT,
                                                 u16* __restrict__ qkb) {
    __shared__ __align__(16) u16 As[2][128 * 64];   // 32 KB
    __shared__ __align__(16) u16 Bs[2][128 * 64];   // 32 KB
    int tid = threadIdx.x, w = tid >> 6, lane = tid & 63;
    int g = lane >> 4, l15 = lane & 15;
    int bid = blockIdx.x;
    int swz = (bid & 7) * 128 + (bid >> 3);   // XCD-chunked, 1024 % 8 == 0
    int bm = swz >> 4, bn = swz & 15;
    int m0 = bm * 128, n0 = bn * 128;
    int wm = w >> 1, wn = w & 1;
    const u16* asrc[4];
    const u16* bsrc[4];
#pragma unroll
    for (int j = 0; j < 4; ++j) {
        int ci = (w * 4 + j) * 64 + lane;
        int row = ci >> 3, cl = (ci & 7) ^ (row & 7);
        asrc[j] = xb + (size_t)(m0 + row) * HID + cl * 8;
        bsrc[j] = wT + (size_t)(n0 + row) * HID + cl * 8;
    }
    f32x4 acc[4][4] = {};
#pragma unroll
    for (int j = 0; j < 4; ++j) {
        gl_lds16(asrc[j], &As[0][(w * 4 + j) * 512]);
        gl_lds16(bsrc[j], &Bs[0][(w * 4 + j) * 512]);
        asrc[j] += 64; bsrc[j] += 64;
    }
    for (int kt = 0; kt < 16; ++kt) {
        int cur = kt & 1;
        asm volatile("s_waitcnt vmcnt(0)" ::: "memory");  // stage(kt) landed
        __builtin_amdgcn_s_barrier();
        __builtin_amdgcn_sched_barrier(0);
        if (kt < 15) {
#pragma unroll
            for (int j = 0; j < 4; ++j) {
                gl_lds16(asrc[j], &As[cur ^ 1][(w * 4 + j) * 512]);
                gl_lds16(bsrc[j], &Bs[cur ^ 1][(w * 4 + j) * 512]);
                asrc[j] += 64; bsrc[j] += 64;
            }
        }
#pragma unroll
        for (int kk = 0; kk < 2; ++kk) {
            bf16x8 af[4], bf[4];
#pragma unroll
            for (int m = 0; m < 4; ++m) {
                int row = wm * 64 + m * 16 + l15;
                int cp = (kk * 4 + g) ^ (row & 7);
                af[m] = *(const bf16x8*)&As[cur][row * 64 + cp * 8];
            }
#pragma unroll
            for (int n = 0; n < 4; ++n) {
                int row = wn * 64 + n * 16 + l15;
                int cp = (kk * 4 + g) ^ (row & 7);
                bf[n] = *(const bf16x8*)&Bs[cur][row * 64 + cp * 8];
            }
#pragma unroll
            for (int m = 0; m < 4; ++m)
#pragma unroll
                for (int n = 0; n < 4; ++n)
                    acc[m][n] = __builtin_amdgcn_mfma_f32_16x16x32_bf16(af[m], bf[n], acc[m][n], 0, 0, 0);
        }
    }
    float scale = (bn < 8) ? C1 : 1.0f;  // query half gets att_scale*log2e
#pragma unroll
    for (int m = 0; m < 4; ++m)
#pragma unroll
        for (int n = 0; n < 4; ++n)
#pragma unroll
            for (int r = 0; r < 4; ++r) {
                int row = m0 + wm * 64 + m * 16 + g * 4 + r;
                int col = n0 + wn * 64 + n * 16 + l15;
                qkb[(size_t)row * 2048 + col] = f2bf(acc[m][n][r] * scale);
            }
}

// ---------------- attention: block = (b, head, 256 q-rows), 512 threads -----
// R17 pairs skeleton (66.2 us) + 3-BUFFER pair pipeline with counted
// vmcnt(6): each pair-stage gets TWO compute phases (~1600 cy) to land.
// Per iter p: issue group G(p+2) = {4 mask loads + 2 gl_lds} = 6 VM ops;
// iter-top vmcnt(6) drains G(p) while G(p+1) stays in flight. Prologue
// groups fenced; last iter peeled with vmcnt(0). Burst size = pairs
// (16 KB/block) -- stays under the L2 pressure point that killed quad (R18).
// LDS 56.5 KB -> 2 blocks/CU unchanged. Buffer hazard: stage(p+2) writes
// buf[(p-1)%3], whose readers finished before this iter's barrier.
__global__ __launch_bounds__(512, 4) void attn(const u16* __restrict__ qkb,
                                               const float* __restrict__ vT,
                                               const u64* __restrict__ bmk,
                                               float* __restrict__ hatt) {
    __shared__ __align__(16) u16 Ks[3][2][64 * 64];  // 48 KB (3 bufs x 2 tiles)
    __shared__ __align__(16) float Vh[2048];         // 8 KB
    __shared__ __align__(16) float Tb[16][4];
    int tid = threadIdx.x, w = tid >> 6, lane = tid & 63;
    int g = lane >> 4, l15 = lane & 15, g4 = g * 4;
    int bid = blockIdx.x;
    int swzb = (bid & 7) * 64 + (bid >> 3);  // XCD-chunk: one (b,h)'s q-tiles share an XCD
    int qt = swzb & 7, h = (swzb >> 3) & 15, b = swzb >> 7;
    int q0 = qt * 256;
    if (tid < 64) Tb[tid >> 2][tid & 3] = (float)(((tid >> 2) >> (tid & 3)) & 1);
    // ---- prologue ----
    int qA = q0 + w * 32 + l15, qB = qA + 16;
    const u16* qrowA = qkb + (size_t)(b * SEQ + qA) * 2048 + h * 64;
    const u16* qrowB = qkb + (size_t)(b * SEQ + qB) * 2048 + h * 64;
    bf16x8 qfA0 = *(const bf16x8*)(qrowA + g * 8);
    bf16x8 qfA1 = *(const bf16x8*)(qrowA + 32 + g * 8);
    bf16x8 qfB0 = *(const bf16x8*)(qrowB + g * 8);
    bf16x8 qfB1 = *(const bf16x8*)(qrowB + 32 + g * 8);
    gl_lds16(vT + ((size_t)b * 16 + h) * SEQ + tid * 4, &Vh[w * 256]);
    const u64* mrowA = bmk + ((size_t)b * SEQ + qA) * 32;
    const u64* mrowB = bmk + ((size_t)b * SEQ + qB) * 32;
    int srow = tid >> 3, scol = (tid & 7) ^ (srow & 7);
    const u16* ksrc = qkb + (size_t)(b * SEQ + srow) * 2048 + 1024 + h * 64 + scol * 8;
    // Q/V drain first so the counted groups below are exactly {masks+stage}
    asm volatile("s_waitcnt vmcnt(0)" ::: "memory");
    // group 0: masks pair0 + stage pair0 -> buf 0
    u64 mAc0 = mrowA[0], mAc1 = mrowA[1], mBc0 = mrowB[0], mBc1 = mrowB[1];
    gl_lds16(ksrc, &Ks[0][0][w * 512]); ksrc += 64 * 2048;
    gl_lds16(ksrc, &Ks[0][1][w * 512]); ksrc += 64 * 2048;
    asm volatile("" ::: "memory");  // pin group order
    // group 1: masks pair1 + stage pair1 -> buf 1
    u64 mAn0 = mrowA[2], mAn1 = mrowA[3], mBn0 = mrowB[2], mBn1 = mrowB[3];
    gl_lds16(ksrc, &Ks[1][0][w * 512]); ksrc += 64 * 2048;
    gl_lds16(ksrc, &Ks[1][1][w * 512]); ksrc += 64 * 2048;
    int e0[4], e1[4];
#pragma unroll
    for (int cb = 0; cb < 4; ++cb) {
        int krow = cb * 16 + l15;
        e0[cb] = krow * 64 + ((g) ^ (krow & 7)) * 8;
        e1[cb] = krow * 64 + ((4 + g) ^ (krow & 7)) * 8;
    }
    float nmA0 = 0.f, nmA1 = 0.f, nmA2 = 0.f, nmA3 = 0.f;
    float dnA0 = 0.f, dnA1 = 0.f, dnA2 = 0.f, dnA3 = 0.f;
    float nmB0 = 0.f, nmB1 = 0.f, nmB2 = 0.f, nmB3 = 0.f;
    float dnB0 = 0.f, dnB1 = 0.f, dnB2 = 0.f, dnB3 = 0.f;
    asm volatile("s_waitcnt lgkmcnt(0)" ::: "memory");  // Tb/Vh ds-writes visible ordering

    auto compute = [&](int kt, const u16* kcur, u64 mwA, u64 mwB) {
        const float* vk = &Vh[kt * 64 + g4];
        u64 shA = mwA >> g4, shB = mwB >> g4;
        u32 aLo = (u32)shA, aHi = (u32)(shA >> 32);
        u32 bLo = (u32)shB, bHi = (u32)(shB >> 32);
        int idxA[4] = {(int)(aLo & 15), (int)((aLo >> 16) & 15),
                       (int)(aHi & 15), (int)((aHi >> 16) & 15)};
        int idxB[4] = {(int)(bLo & 15), (int)((bLo >> 16) & 15),
                       (int)(bHi & 15), (int)((bHi >> 16) & 15)};
#pragma unroll
        for (int cb = 0; cb < 4; ++cb) {
            bf16x8 kf0 = *(const bf16x8*)&kcur[e0[cb]];
            bf16x8 kf1 = *(const bf16x8*)&kcur[e1[cb]];
            f32x4 aA = {0.f, 0.f, 0.f, 0.f}, aB = {0.f, 0.f, 0.f, 0.f};
            aA = __builtin_amdgcn_mfma_f32_16x16x32_bf16(kf0, qfA0, aA, 0, 0, 0);
            aA = __builtin_amdgcn_mfma_f32_16x16x32_bf16(kf1, qfA1, aA, 0, 0, 0);
            aB = __builtin_amdgcn_mfma_f32_16x16x32_bf16(kf0, qfB0, aB, 0, 0, 0);
            aB = __builtin_amdgcn_mfma_f32_16x16x32_bf16(kf1, qfB1, aB, 0, 0, 0);
            const float4 mA4 = *(const float4*)&Tb[idxA[cb]][0];
            const float4 mB4 = *(const float4*)&Tb[idxB[cb]][0];
            const float4 vv = *(const float4*)&vk[cb * 16];
            float pA0 = EXP2(aA[0]) * mA4.x, pA1 = EXP2(aA[1]) * mA4.y;
            float pA2 = EXP2(aA[2]) * mA4.z, pA3 = EXP2(aA[3]) * mA4.w;
            float pB0 = EXP2(aB[0]) * mB4.x, pB1 = EXP2(aB[1]) * mB4.y;
            float pB2 = EXP2(aB[2]) * mB4.z, pB3 = EXP2(aB[3]) * mB4.w;
            dnA0 += pA0; dnA1 += pA1; dnA2 += pA2; dnA3 += pA3;
            dnB0 += pB0; dnB1 += pB1; dnB2 += pB2; dnB3 += pB3;
            nmA0 = fmaf(pA0, vv.x, nmA0); nmA1 = fmaf(pA1, vv.y, nmA1);
            nmA2 = fmaf(pA2, vv.z, nmA2); nmA3 = fmaf(pA3, vv.w, nmA3);
            nmB0 = fmaf(pB0, vv.x, nmB0); nmB1 = fmaf(pB1, vv.y, nmB1);
            nmB2 = fmaf(pB2, vv.z, nmB2); nmB3 = fmaf(pB3, vv.w, nmB3);
        }
    };

    for (int p = 0; p < 15; ++p) {
        // steady state: outstanding = G(p) + G(p+1), 6 ops each;
        // vmcnt(6) drains G(p) = {masks p, stage p}, leaves G(p+1) in flight.
        asm volatile("s_waitcnt vmcnt(6)" ::: "memory");
        __builtin_amdgcn_s_barrier();  // all waves done reading buf[(p-1)%3]
        __builtin_amdgcn_sched_barrier(0);
        u64 nA0 = 0, nA1 = 0, nB0 = 0, nB1 = 0;
        if (p < 14) {  // issue G(p+2): masks pair p+2 + stage into buf (p+2)%3
            nA0 = mrowA[2 * p + 4]; nA1 = mrowA[2 * p + 5];
            nB0 = mrowB[2 * p + 4]; nB1 = mrowB[2 * p + 5];
            gl_lds16(ksrc, &Ks[(p + 2) % 3][0][w * 512]); ksrc += 64 * 2048;
            gl_lds16(ksrc, &Ks[(p + 2) % 3][1][w * 512]); ksrc += 64 * 2048;
        }
        compute(2 * p,     &Ks[p % 3][0][0], mAc0, mBc0);
        compute(2 * p + 1, &Ks[p % 3][1][0], mAc1, mBc1);
        mAc0 = mAn0; mAc1 = mAn1; mBc0 = mBn0; mBc1 = mBn1;
        mAn0 = nA0; mAn1 = nA1; mBn0 = nB0; mBn1 = nB1;
    }
    // peeled last pair (p=15): only G(15) outstanding -> full drain
    asm volatile("s_waitcnt vmcnt(0)" ::: "memory");
    __builtin_amdgcn_s_barrier();
    __builtin_amdgcn_sched_barrier(0);
    compute(30, &Ks[15 % 3][0][0], mAc0, mBc0);
    compute(31, &Ks[15 % 3][1][0], mAc1, mBc1);

    float numA = (nmA0 + nmA1) + (nmA2 + nmA3);
    float denA = (dnA0 + dnA1) + (dnA2 + dnA3);
    float numB = (nmB0 + nmB1) + (nmB2 + nmB3);
    float denB = (dnB0 + dnB1) + (dnB2 + dnB3);
    numA += __shfl_xor(numA, 16); denA += __shfl_xor(denA, 16);
    numA += __shfl_xor(numA, 32); denA += __shfl_xor(denA, 32);
    numB += __shfl_xor(numB, 16); denB += __shfl_xor(denB, 16);
    numB += __shfl_xor(numB, 32); denB += __shfl_xor(denB, 32);
    if (g == 0) {
        hatt[((size_t)b * SEQ + qA) * 16 + h] = numA / denA;
        hatt[((size_t)b * SEQ + qB) * 16 + h] = numB / denB;
    }
}

// ---------------- epilogue: sum 16 heads, last-row mask, sigmoid ------------
__global__ void epi(const float* __restrict__ hatt, const void* __restrict__ mask,
                    const int* __restrict__ flag, float* __restrict__ out) {
    int i = blockIdx.x * 256 + threadIdx.x;  // 8192
    int b = i >> 11, q = i & 2047;
    const float4* hp = (const float4*)(hatt + (size_t)i * 16);
    float t = 0.f;
#pragma unroll
    for (int j = 0; j < 4; ++j) {
        float4 u = hp[j];
        t += u.x + u.y + u.z + u.w;
    }
    size_t mi = ((size_t)b * SEQ + (SEQ - 1)) * SEQ + q;
    int m;
    if (*flag) m = ((const int*)mask)[mi];
    else       m = ((const unsigned char*)mask)[mi];
    out[i] = m ? 0.f : 1.f / (1.f + expf(-t));
}

extern "C" void kernel_launch(void* const* d_in, const int* in_sizes, int n_in,
                              void* d_out, int out_size, void* d_ws, size_t ws_size,
                              hipStream_t stream) {
    const float* x = (const float*)d_in[0];
    const void* mask = d_in[1];
    const float* Wqk = (const float*)d_in[2];
    const float* Wv = (const float*)d_in[3];
    float* out = (float*)d_out;
    char* ws = (char*)d_ws;
    u16* xb = (u16*)(ws + 0);                  // 16,777,216 B (dead after proj_gemm)
    u16* wT = (u16*)(ws + 16777216);           //  4,194,304 B
    u16* qkb = (u16*)(ws + 20971520);          // 33,554,432 B
    float* vT = (float*)(ws + 54525952);       //    524,288 B
    u64* bm = (u64*)(ws + 55050240);           //  2,097,152 B
    float* hatt = (float*)(ws + 0);            //    524,288 B (aliases xb; written after proj reads xb)
    int* flag = (int*)(ws + 57147392);         //          4 B

    front<<<2561, 256, 0, stream>>>(x, Wv, Wqk, (const unsigned char*)mask,
                                    xb, vT, wT, flag);
    bitpack<<<8192, 256, 0, stream>>>(mask, flag, bm);
    proj_gemm<<<1024, 256, 0, stream>>>(xb, wT, qkb);
    attn<<<512, 512, 0, stream>>>(qkb, vT, bm, hatt);
    epi<<<32, 256, 0, stream>>>(hatt, mask, flag, out);
}

// Round 20
// 152.359 us; speedup vs baseline: 1.4986x; 1.4986x over previous
//
#include <hip/hip_runtime.h>

typedef unsigned short u16;
typedef unsigned int u32;
typedef unsigned long long u64;
typedef __attribute__((ext_vector_type(8))) short bf16x8;
typedef __attribute__((ext_vector_type(4))) float f32x4;

#define BATCH 4
#define SEQ 2048
#define HID 1024
#define NHEAD 16
#define HDIM 64
// att_scale * log2(e): p = exp2(raw_score * C1); folded into Q at proj epilogue
#define C1 0.18033688011112042f

#if __has_builtin(__builtin_amdgcn_exp2f)
#define EXP2(x) __builtin_amdgcn_exp2f(x)
#else
#define EXP2(x) exp2f(x)
#endif

__device__ __forceinline__ u16 f2bf(float f) {
    u32 u = __builtin_bit_cast(u32, f);
    u += 0x7fffu + ((u >> 16) & 1u);
    return (u16)(u >> 16);
}

__device__ __forceinline__ void gl_lds16(const void* g, void* l) {
    __builtin_amdgcn_global_load_lds((const __attribute__((address_space(1))) u32*)g,
                                     (__attribute__((address_space(3))) u32*)l, 16, 0, 0);
}

// ---------------- front: convxv (0-511) | transw (512-2559) | flagk (2560) --
// convxv: x fp32 -> bf16 AND value = x @ W_v (one x read serves both).
//   NOTE: h4 iterated in uniform order across threads -> Wv operands are
//   wave-uniform per step (compiler hoists to scalar/broadcast loads).
//   Do NOT rotate per-lane (R15 regression: broke the broadcast, +9 us).
// transw: W_qk (1024x2048) -> wT bf16 (2048x1024).
// flagk: mask dtype probe -> flag=1 int32 mask, 0 byte mask.
__global__ __launch_bounds__(256) void front(const float* __restrict__ x,
                                             const float* __restrict__ Wv,
                                             const float* __restrict__ W,
                                             const unsigned char* __restrict__ mask,
                                             u16* __restrict__ xb,
                                             float* __restrict__ vT,
                                             u16* __restrict__ wT,
                                             int* __restrict__ flag) {
    __shared__ __align__(16) float smem[16 * 1024];  // 64 KB, role-cast below
    int bid = blockIdx.x;
    if (bid < 512) {
        // ---- convxv ----
        float* xs = smem;
        int s0 = bid * 16;
        const float4* xg = (const float4*)(x + (size_t)s0 * HID);
        float4* xd = (float4*)xs;
        ushort4* xo = (ushort4*)(xb + (size_t)s0 * HID);
#pragma unroll
        for (int j = 0; j < 16; ++j) {
            int i = j * 256 + threadIdx.x;
            float4 v = xg[i];
            xd[i] = v;
            ushort4 o;
            o.x = f2bf(v.x); o.y = f2bf(v.y); o.z = f2bf(v.z); o.w = f2bf(v.w);
            xo[i] = o;
        }
        __syncthreads();
        int sl = threadIdx.x >> 4, n = threadIdx.x & 15;
        const float4* xrow = (const float4*)&xs[sl * HID];
        float acc = 0.f;
        for (int h4 = 0; h4 < 256; ++h4) {
            float4 xv = xrow[h4];
            acc += xv.x * Wv[(h4 * 4 + 0) * 16 + n] + xv.y * Wv[(h4 * 4 + 1) * 16 + n]
                 + xv.z * Wv[(h4 * 4 + 2) * 16 + n] + xv.w * Wv[(h4 * 4 + 3) * 16 + n];
        }
        int s = s0 + sl;
        int b = s >> 11, q = s & 2047;
        vT[((size_t)b * 16 + n) * SEQ + q] = acc;
    } else if (bid < 2560) {
        // ---- transw ----
        float (*t)[33] = (float (*)[33])smem;
        int tb = bid - 512;
        int nb = tb & 63, hb = tb >> 6;
        int tx = threadIdx.x & 31, ty = threadIdx.x >> 5;
#pragma unroll
        for (int i = 0; i < 4; ++i)
            t[ty + i * 8][tx] = W[(size_t)(hb * 32 + ty + i * 8) * 2048 + nb * 32 + tx];
        __syncthreads();
#pragma unroll
        for (int i = 0; i < 4; ++i)
            wT[(size_t)(nb * 32 + ty + i * 8) * 1024 + hb * 32 + tx] = f2bf(t[tx][ty + i * 8]);
    } else {
        // ---- flagk: probe first 64 KB of mask ----
        int* any = (int*)smem;
        if (threadIdx.x == 0) *any = 0;
        __syncthreads();
        const uint4* m4 = (const uint4*)mask;
        u32 acc = 0;
#pragma unroll
        for (int j = 0; j < 16; ++j) {
            uint4 v = m4[threadIdx.x + j * 256];
            acc |= (v.x | v.y | v.z | v.w) & 0xFFFFFF00u;
        }
        if (acc) atomicOr(any, 1);
        __syncthreads();
        if (threadIdx.x == 0) *flag = (*any == 0) ? 1 : 0;
    }
}

// ---------------- bitpack mask: KEEP-bits (1 = unmasked) via ballot ---------
__global__ void bitpack(const void* __restrict__ mask, const int* __restrict__ flag,
                        u64* __restrict__ bm) {
    int base = blockIdx.x * 2048 + threadIdx.x;  // grid 8192, covers 16777216
    int fl = *flag;
#pragma unroll
    for (int k = 0; k < 8; ++k) {
        int i = base + k * 256;
        int v;
        if (fl) v = ((const int*)mask)[i];
        else    v = ((const unsigned char*)mask)[i];
        u64 bits = __ballot(v == 0);  // keep-bit; lanes cover consecutive i
        if ((threadIdx.x & 63) == 0) bm[i >> 6] = bits;
    }
}

// ---------------- proj GEMM: qkb(8192x2048) = xb(8192x1024) @ wT^T ----------
// 128x128 tile, BK=64, double-buffered LDS (64 KB), counted pipeline.
__global__ __launch_bounds__(256) void proj_gemm(const u16* __restrict__ xb,
                                                 const u16* __restrict__ wT,
                                                 u16* __restrict__ qkb) {
    __shared__ __align__(16) u16 As[2][128 * 64];   // 32 KB
    __shared__ __align__(16) u16 Bs[2][128 * 64];   // 32 KB
    int tid = threadIdx.x, w = tid >> 6, lane = tid & 63;
    int g = lane >> 4, l15 = lane & 15;
    int bid = blockIdx.x;
    int swz = (bid & 7) * 128 + (bid >> 3);   // XCD-chunked, 1024 % 8 == 0
    int bm = swz >> 4, bn = swz & 15;
    int m0 = bm * 128, n0 = bn * 128;
    int wm = w >> 1, wn = w & 1;
    const u16* asrc[4];
    const u16* bsrc[4];
#pragma unroll
    for (int j = 0; j < 4; ++j) {
        int ci = (w * 4 + j) * 64 + lane;
        int row = ci >> 3, cl = (ci & 7) ^ (row & 7);
        asrc[j] = xb + (size_t)(m0 + row) * HID + cl * 8;
        bsrc[j] = wT + (size_t)(n0 + row) * HID + cl * 8;
    }
    f32x4 acc[4][4] = {};
#pragma unroll
    for (int j = 0; j < 4; ++j) {
        gl_lds16(asrc[j], &As[0][(w * 4 + j) * 512]);
        gl_lds16(bsrc[j], &Bs[0][(w * 4 + j) * 512]);
        asrc[j] += 64; bsrc[j] += 64;
    }
    for (int kt = 0; kt < 16; ++kt) {
        int cur = kt & 1;
        asm volatile("s_waitcnt vmcnt(0)" ::: "memory");  // stage(kt) landed
        __builtin_amdgcn_s_barrier();
        __builtin_amdgcn_sched_barrier(0);
        if (kt < 15) {
#pragma unroll
            for (int j = 0; j < 4; ++j) {
                gl_lds16(asrc[j], &As[cur ^ 1][(w * 4 + j) * 512]);
                gl_lds16(bsrc[j], &Bs[cur ^ 1][(w * 4 + j) * 512]);
                asrc[j] += 64; bsrc[j] += 64;
            }
        }
#pragma unroll
        for (int kk = 0; kk < 2; ++kk) {
            bf16x8 af[4], bf[4];
#pragma unroll
            for (int m = 0; m < 4; ++m) {
                int row = wm * 64 + m * 16 + l15;
                int cp = (kk * 4 + g) ^ (row & 7);
                af[m] = *(const bf16x8*)&As[cur][row * 64 + cp * 8];
            }
#pragma unroll
            for (int n = 0; n < 4; ++n) {
                int row = wn * 64 + n * 16 + l15;
                int cp = (kk * 4 + g) ^ (row & 7);
                bf[n] = *(const bf16x8*)&Bs[cur][row * 64 + cp * 8];
            }
#pragma unroll
            for (int m = 0; m < 4; ++m)
#pragma unroll
                for (int n = 0; n < 4; ++n)
                    acc[m][n] = __builtin_amdgcn_mfma_f32_16x16x32_bf16(af[m], bf[n], acc[m][n], 0, 0, 0);
        }
    }
    float scale = (bn < 8) ? C1 : 1.0f;  // query half gets att_scale*log2e
#pragma unroll
    for (int m = 0; m < 4; ++m)
#pragma unroll
        for (int n = 0; n < 4; ++n)
#pragma unroll
            for (int r = 0; r < 4; ++r) {
                int row = m0 + wm * 64 + m * 16 + g * 4 + r;
                int col = n0 + wn * 64 + n * 16 + l15;
                qkb[(size_t)row * 2048 + col] = f2bf(acc[m][n][r] * scale);
            }
}

// ---------------- attention: block = (b, head, 256 q-rows), 512 threads -----
// R17 pairs kernel (measured 66.2 us — best of 8 structural probes).
// 2 k-tiles per barrier (16 barriers). Dbuf pairs: wait vmcnt(0) -> barrier
// -> stage next pair + prefetch masks -> compute 2 tiles (zero VM ops in
// compute). Simple 2-buffer rotation keeps the register allocator happy
// (3-buffer %3 + counted vmcnt spilled to scratch, R19: ~146 us).
__global__ __launch_bounds__(512, 4) void attn(const u16* __restrict__ qkb,
                                               const float* __restrict__ vT,
                                               const u64* __restrict__ bmk,
                                               float* __restrict__ hatt) {
    __shared__ __align__(16) u16 Ks[2][2][64 * 64];  // 32 KB (2 bufs x 2 tiles)
    __shared__ __align__(16) float Vh[2048];         // 8 KB
    __shared__ __align__(16) float Tb[16][4];
    int tid = threadIdx.x, w = tid >> 6, lane = tid & 63;
    int g = lane >> 4, l15 = lane & 15, g4 = g * 4;
    int bid = blockIdx.x;
    int swzb = (bid & 7) * 64 + (bid >> 3);  // XCD-chunk: one (b,h)'s q-tiles share an XCD
    int qt = swzb & 7, h = (swzb >> 3) & 15, b = swzb >> 7;
    int q0 = qt * 256;
    if (tid < 64) Tb[tid >> 2][tid & 3] = (float)(((tid >> 2) >> (tid & 3)) & 1);
    // ---- prologue ----
    int qA = q0 + w * 32 + l15, qB = qA + 16;
    const u16* qrowA = qkb + (size_t)(b * SEQ + qA) * 2048 + h * 64;
    const u16* qrowB = qkb + (size_t)(b * SEQ + qB) * 2048 + h * 64;
    bf16x8 qfA0 = *(const bf16x8*)(qrowA + g * 8);
    bf16x8 qfA1 = *(const bf16x8*)(qrowA + 32 + g * 8);
    bf16x8 qfB0 = *(const bf16x8*)(qrowB + g * 8);
    bf16x8 qfB1 = *(const bf16x8*)(qrowB + 32 + g * 8);
    gl_lds16(vT + ((size_t)b * 16 + h) * SEQ + tid * 4, &Vh[w * 256]);
    const u64* mrowA = bmk + ((size_t)b * SEQ + qA) * 32;
    const u64* mrowB = bmk + ((size_t)b * SEQ + qB) * 32;
    int srow = tid >> 3, scol = (tid & 7) ^ (srow & 7);
    const u16* ksrc = qkb + (size_t)(b * SEQ + srow) * 2048 + 1024 + h * 64 + scol * 8;
    // stage pair 0 (tiles 0,1) into buf 0; masks for pair 0
    u64 mA0 = mrowA[0], mA1 = mrowA[1], mB0 = mrowB[0], mB1 = mrowB[1];
    gl_lds16(ksrc, &Ks[0][0][w * 512]); ksrc += 64 * 2048;
    gl_lds16(ksrc, &Ks[0][1][w * 512]); ksrc += 64 * 2048;
    int e0[4], e1[4];
#pragma unroll
    for (int cb = 0; cb < 4; ++cb) {
        int krow = cb * 16 + l15;
        e0[cb] = krow * 64 + ((g) ^ (krow & 7)) * 8;
        e1[cb] = krow * 64 + ((4 + g) ^ (krow & 7)) * 8;
    }
    float nmA0 = 0.f, nmA1 = 0.f, nmA2 = 0.f, nmA3 = 0.f;
    float dnA0 = 0.f, dnA1 = 0.f, dnA2 = 0.f, dnA3 = 0.f;
    float nmB0 = 0.f, nmB1 = 0.f, nmB2 = 0.f, nmB3 = 0.f;
    float dnB0 = 0.f, dnB1 = 0.f, dnB2 = 0.f, dnB3 = 0.f;
    asm volatile("s_waitcnt vmcnt(0) lgkmcnt(0)" ::: "memory");  // pair0, V, Q, masks, Tb
    __builtin_amdgcn_s_barrier();

    auto compute = [&](int kt, const u16* kcur, u64 mwA, u64 mwB) {
        const float* vk = &Vh[kt * 64 + g4];
        u64 shA = mwA >> g4, shB = mwB >> g4;
        u32 aLo = (u32)shA, aHi = (u32)(shA >> 32);
        u32 bLo = (u32)shB, bHi = (u32)(shB >> 32);
        int idxA[4] = {(int)(aLo & 15), (int)((aLo >> 16) & 15),
                       (int)(aHi & 15), (int)((aHi >> 16) & 15)};
        int idxB[4] = {(int)(bLo & 15), (int)((bLo >> 16) & 15),
                       (int)(bHi & 15), (int)((bHi >> 16) & 15)};
#pragma unroll
        for (int cb = 0; cb < 4; ++cb) {
            bf16x8 kf0 = *(const bf16x8*)&kcur[e0[cb]];
            bf16x8 kf1 = *(const bf16x8*)&kcur[e1[cb]];
            f32x4 aA = {0.f, 0.f, 0.f, 0.f}, aB = {0.f, 0.f, 0.f, 0.f};
            aA = __builtin_amdgcn_mfma_f32_16x16x32_bf16(kf0, qfA0, aA, 0, 0, 0);
            aA = __builtin_amdgcn_mfma_f32_16x16x32_bf16(kf1, qfA1, aA, 0, 0, 0);
            aB = __builtin_amdgcn_mfma_f32_16x16x32_bf16(kf0, qfB0, aB, 0, 0, 0);
            aB = __builtin_amdgcn_mfma_f32_16x16x32_bf16(kf1, qfB1, aB, 0, 0, 0);
            const float4 mA4 = *(const float4*)&Tb[idxA[cb]][0];
            const float4 mB4 = *(const float4*)&Tb[idxB[cb]][0];
            const float4 vv = *(const float4*)&vk[cb * 16];
            float pA0 = EXP2(aA[0]) * mA4.x, pA1 = EXP2(aA[1]) * mA4.y;
            float pA2 = EXP2(aA[2]) * mA4.z, pA3 = EXP2(aA[3]) * mA4.w;
            float pB0 = EXP2(aB[0]) * mB4.x, pB1 = EXP2(aB[1]) * mB4.y;
            float pB2 = EXP2(aB[2]) * mB4.z, pB3 = EXP2(aB[3]) * mB4.w;
            dnA0 += pA0; dnA1 += pA1; dnA2 += pA2; dnA3 += pA3;
            dnB0 += pB0; dnB1 += pB1; dnB2 += pB2; dnB3 += pB3;
            nmA0 = fmaf(pA0, vv.x, nmA0); nmA1 = fmaf(pA1, vv.y, nmA1);
            nmA2 = fmaf(pA2, vv.z, nmA2); nmA3 = fmaf(pA3, vv.w, nmA3);
            nmB0 = fmaf(pB0, vv.x, nmB0); nmB1 = fmaf(pB1, vv.y, nmB1);
            nmB2 = fmaf(pB2, vv.z, nmB2); nmB3 = fmaf(pB3, vv.w, nmB3);
        }
    };

    for (int p = 0; p < 16; ++p) {
        asm volatile("s_waitcnt vmcnt(0)" ::: "memory");  // pair p staged, masks landed
        __builtin_amdgcn_s_barrier();                     // all waves done with buf (p^1)
        __builtin_amdgcn_sched_barrier(0);
        u64 nA0 = 0, nA1 = 0, nB0 = 0, nB1 = 0;
        if (p < 15) {  // stage pair p+1 into the other buffer; prefetch its masks
            gl_lds16(ksrc, &Ks[(p + 1) & 1][0][w * 512]); ksrc += 64 * 2048;
            gl_lds16(ksrc, &Ks[(p + 1) & 1][1][w * 512]); ksrc += 64 * 2048;
            nA0 = mrowA[2 * p + 2]; nA1 = mrowA[2 * p + 3];
            nB0 = mrowB[2 * p + 2]; nB1 = mrowB[2 * p + 3];
        }
        compute(2 * p,     &Ks[p & 1][0][0], mA0, mB0);
        compute(2 * p + 1, &Ks[p & 1][1][0], mA1, mB1);
        mA0 = nA0; mA1 = nA1; mB0 = nB0; mB1 = nB1;
    }

    float numA = (nmA0 + nmA1) + (nmA2 + nmA3);
    float denA = (dnA0 + dnA1) + (dnA2 + dnA3);
    float numB = (nmB0 + nmB1) + (nmB2 + nmB3);
    float denB = (dnB0 + dnB1) + (dnB2 + dnB3);
    numA += __shfl_xor(numA, 16); denA += __shfl_xor(denA, 16);
    numA += __shfl_xor(numA, 32); denA += __shfl_xor(denA, 32);
    numB += __shfl_xor(numB, 16); denB += __shfl_xor(denB, 16);
    numB += __shfl_xor(numB, 32); denB += __shfl_xor(denB, 32);
    if (g == 0) {
        hatt[((size_t)b * SEQ + qA) * 16 + h] = numA / denA;
        hatt[((size_t)b * SEQ + qB) * 16 + h] = numB / denB;
    }
}

// ---------------- epilogue: sum 16 heads, last-row mask, sigmoid ------------
__global__ void epi(const float* __restrict__ hatt, const void* __restrict__ mask,
                    const int* __restrict__ flag, float* __restrict__ out) {
    int i = blockIdx.x * 256 + threadIdx.x;  // 8192
    int b = i >> 11, q = i & 2047;
    const float4* hp = (const float4*)(hatt + (size_t)i * 16);
    float t = 0.f;
#pragma unroll
    for (int j = 0; j < 4; ++j) {
        float4 u = hp[j];
        t += u.x + u.y + u.z + u.w;
    }
    size_t mi = ((size_t)b * SEQ + (SEQ - 1)) * SEQ + q;
    int m;
    if (*flag) m = ((const int*)mask)[mi];
    else       m = ((const unsigned char*)mask)[mi];
    out[i] = m ? 0.f : 1.f / (1.f + expf(-t));
}

extern "C" void kernel_launch(void* const* d_in, const int* in_sizes, int n_in,
                              void* d_out, int out_size, void* d_ws, size_t ws_size,
                              hipStream_t stream) {
    const float* x = (const float*)d_in[0];
    const void* mask = d_in[1];
    const float* Wqk = (const float*)d_in[2];
    const float* Wv = (const float*)d_in[3];
    float* out = (float*)d_out;
    char* ws = (char*)d_ws;
    u16* xb = (u16*)(ws + 0);                  // 16,777,216 B (dead after proj_gemm)
    u16* wT = (u16*)(ws + 16777216);           //  4,194,304 B
    u16* qkb = (u16*)(ws + 20971520);          // 33,554,432 B
    float* vT = (float*)(ws + 54525952);       //    524,288 B
    u64* bm = (u64*)(ws + 55050240);           //  2,097,152 B
    float* hatt = (float*)(ws + 0);            //    524,288 B (aliases xb; written after proj reads xb)
    int* flag = (int*)(ws + 57147392);         //          4 B

    front<<<2561, 256, 0, stream>>>(x, Wv, Wqk, (const unsigned char*)mask,
                                    xb, vT, wT, flag);
    bitpack<<<8192, 256, 0, stream>>>(mask, flag, bm);
    proj_gemm<<<1024, 256, 0, stream>>>(xb, wT, qkb);
    attn<<<512, 512, 0, stream>>>(qkb, vT, bm, hatt);
    epi<<<32, 256, 0, stream>>>(hatt, mask, flag, out);
}